// Round 3
// baseline (1596.585 us; speedup 1.0000x reference)
//
#include <hip/hip_runtime.h>
#include <math.h>

#define N_NODES 100000
#define N_EDGES 3200000
#define N_GRAPHS 64
#define BW 128                               // nodes per bucket
#define NBUCK ((N_NODES + BW - 1) / BW)      // 782

// ---------------- bucket histogram (LDS-combined) ----------------
__global__ void k_bhist(const int* __restrict__ dst, unsigned int* __restrict__ bhist) {
    __shared__ unsigned int h[NBUCK];
    for (int i = threadIdx.x; i < NBUCK; i += blockDim.x) h[i] = 0u;
    __syncthreads();
    for (int e = blockIdx.x * blockDim.x + threadIdx.x; e < N_EDGES; e += gridDim.x * blockDim.x)
        atomicAdd(&h[dst[e] >> 7], 1u);
    __syncthreads();
    for (int i = threadIdx.x; i < NBUCK; i += blockDim.x)
        if (h[i]) atomicAdd(&bhist[i], h[i]);
}

// ---------------- one-block exclusive scan of NBUCK (<1024) ----------------
__global__ void k_scan(const unsigned int* __restrict__ bhist,
                       unsigned int* __restrict__ off, unsigned int* __restrict__ cur) {
    __shared__ unsigned int sd[1024];
    int t = threadIdx.x;
    unsigned int v = (t < NBUCK) ? bhist[t] : 0u;
    sd[t] = v;
    __syncthreads();
    for (int o = 1; o < 1024; o <<= 1) {
        unsigned int tv = (t >= o) ? sd[t - o] : 0u;
        __syncthreads();
        sd[t] += tv;
        __syncthreads();
    }
    if (t < NBUCK) { unsigned int ex = sd[t] - v; off[t] = ex; cur[t] = ex; }
    if (t == 1023) off[NBUCK] = sd[1023];
}

// ---------------- edge partition: packed u32 = (src<<7)|(dst&127) ----------------
__global__ void k_part(const int* __restrict__ src, const int* __restrict__ dst,
                       unsigned int* __restrict__ cur, unsigned int* __restrict__ packed) {
    int e = blockIdx.x * blockDim.x + threadIdx.x;
    if (e < N_EDGES) {
        int d = dst[e];
        unsigned int pos = atomicAdd(&cur[d >> 7], 1u);
        packed[pos] = ((unsigned int)src[e] << 7) | (unsigned int)(d & 127);
    }
}

// ---------------- per-bucket degree -> dinv, s ----------------
__global__ void k_deg(const unsigned int* __restrict__ off, const unsigned int* __restrict__ packed,
                      const float* __restrict__ x, float* __restrict__ dinv, float* __restrict__ s) {
    __shared__ unsigned int cnt[BW];
    int b = blockIdx.x;
    for (int i = threadIdx.x; i < BW; i += blockDim.x) cnt[i] = 0u;
    __syncthreads();
    unsigned int e0 = off[b], e1 = off[b + 1];
    for (unsigned int e = e0 + threadIdx.x; e < e1; e += blockDim.x)
        atomicAdd(&cnt[packed[e] & 127u], 1u);
    __syncthreads();
    int n = b * BW + threadIdx.x;
    if (threadIdx.x < BW && n < N_NODES) {
        float di = 1.0f / sqrtf((float)(cnt[threadIdx.x] + 1u));  // +1 self-loop
        dinv[n] = di;
        s[n] = x[n] * di;
    }
}

// graph node counts via binary search on sorted batch — no atomics
__global__ void k_gcnt(const int* __restrict__ batch, float* __restrict__ gcnt) {
    __shared__ int lb[N_GRAPHS + 1];
    int b = threadIdx.x;
    if (b <= N_GRAPHS) {
        int lo = 0, hi = N_NODES;
        while (lo < hi) {
            int mid = (lo + hi) >> 1;
            if (batch[mid] < b) lo = mid + 1; else hi = mid;
        }
        lb[b] = lo;
    }
    __syncthreads();
    if (b < N_GRAPHS) gcnt[b] = (float)(lb[b + 1] - lb[b]);
}

// ---------------- layer 1: LDS scalar agg + fused node MLP -> q ----------------
__global__ void k_l1(const unsigned int* __restrict__ off, const unsigned int* __restrict__ packed,
                     const float* __restrict__ dinv, const float* __restrict__ s,
                     const float* __restrict__ W1, const float* __restrict__ b1,
                     const float* __restrict__ W2, float* __restrict__ q) {
    __shared__ float acc[BW];
    __shared__ float sW2[64 * 32];
    __shared__ float sW1[64], sb1[64];
    for (int i = threadIdx.x; i < BW; i += blockDim.x) acc[i] = 0.0f;
    for (int i = threadIdx.x; i < 64 * 32; i += blockDim.x) sW2[i] = W2[i];
    if (threadIdx.x < 64) { sW1[threadIdx.x] = W1[threadIdx.x]; sb1[threadIdx.x] = b1[threadIdx.x]; }
    __syncthreads();
    int b = blockIdx.x;
    unsigned int e0 = off[b], e1 = off[b + 1];
    for (unsigned int e = e0 + threadIdx.x; e < e1; e += blockDim.x) {
        unsigned int p = packed[e];
        atomicAdd(&acc[p & 127u], s[p >> 7]);
    }
    __syncthreads();
    int t = threadIdx.x;
    int n = b * BW + t;
    if (t < BW && n < N_NODES) {
        float di = dinv[n];
        float tt = di * (acc[t] + s[n]);
        float p[32];
#pragma unroll
        for (int k = 0; k < 32; k++) p[k] = 0.0f;
        for (int j = 0; j < 64; j++) {
            float h = fmaxf(tt * sW1[j] + sb1[j], 0.0f);
#pragma unroll
            for (int k = 0; k < 32; k++) p[k] += h * sW2[j * 32 + k];
        }
#pragma unroll
        for (int k = 0; k < 32; k++) q[(size_t)n * 32 + k] = p[k] * di;
    }
}

// ---------------- layer 2: LDS row agg + relu + fused pooling ----------------
__global__ void k_l2(const unsigned int* __restrict__ off, const unsigned int* __restrict__ packed,
                     const float* __restrict__ q, const float* __restrict__ dinv,
                     const float* __restrict__ b2, const int* __restrict__ batch,
                     float* __restrict__ gsum) {
    __shared__ float acc[BW * 32];  // 16 KB
    for (int i = threadIdx.x; i < BW * 32; i += blockDim.x) acc[i] = 0.0f;
    __syncthreads();
    int b = blockIdx.x;
    unsigned int e0 = off[b], e1 = off[b + 1];
    int g = threadIdx.x >> 5;   // 8 groups of 32 lanes
    int k = threadIdx.x & 31;
    for (unsigned int e = e0 + g; e < e1; e += 8) {
        unsigned int p = packed[e];                 // broadcast within group
        int local = (int)(p & 127u);
        int src = (int)(p >> 7);
        atomicAdd(&acc[local * 32 + k], q[(size_t)src * 32 + k]);  // bank k, conflict-free
    }
    __syncthreads();
    // epilogue: relu + run-accumulated pooling (batch sorted)
    float racc = 0.0f;
    int curg = -1;
    for (int i = g; i < BW; i += 8) {
        int n = b * BW + i;
        if (n >= N_NODES) break;
        float v = fmaxf(dinv[n] * (acc[i * 32 + k] + q[(size_t)n * 32 + k]) + b2[k], 0.0f);
        int gb = batch[n];
        if (gb != curg) {
            if (curg >= 0) atomicAdd(&gsum[curg * 32 + k], racc);
            racc = 0.0f; curg = gb;
        }
        racc += v;
    }
    if (curg >= 0) atomicAdd(&gsum[curg * 32 + k], racc);
}

// ---------------- readout ----------------
__global__ void k_readout(const float* __restrict__ gsum, const float* __restrict__ gcnt,
                          const float* __restrict__ Wfc, const float* __restrict__ bfc,
                          float* __restrict__ out) {
    int b = threadIdx.x;
    if (b < N_GRAPHS) {
        float inv = 1.0f / fmaxf(gcnt[b], 1.0f);
        float acc = bfc[0];
#pragma unroll
        for (int k = 0; k < 32; k++) acc += gsum[b * 32 + k] * inv * Wfc[k];
        out[b] = 1.0f / (1.0f + expf(-acc));
    }
}

// ---------------- launch ----------------
extern "C" void kernel_launch(void* const* d_in, const int* in_sizes, int n_in,
                              void* d_out, int out_size, void* d_ws, size_t ws_size,
                              hipStream_t stream) {
    const float* x    = (const float*)d_in[0];
    const int*   ei   = (const int*)d_in[1];
    const int*   batch= (const int*)d_in[2];
    const float* W1   = (const float*)d_in[3];
    const float* b1   = (const float*)d_in[4];
    const float* W2   = (const float*)d_in[5];
    const float* b2   = (const float*)d_in[6];
    const float* Wfc  = (const float*)d_in[7];
    const float* bfc  = (const float*)d_in[8];
    float* out = (float*)d_out;

    const int* srcIdx = ei;
    const int* dstIdx = ei + N_EDGES;

    char* w = (char*)d_ws;
    unsigned int* bhist  = (unsigned int*)w; w += ((NBUCK + 64) & ~63) * 4;
    unsigned int* off    = (unsigned int*)w; w += ((NBUCK + 1 + 63) & ~63) * 4;
    unsigned int* cur    = (unsigned int*)w; w += ((NBUCK + 64) & ~63) * 4;
    unsigned int* packed = (unsigned int*)w; w += (size_t)N_EDGES * 4;
    float* dinv = (float*)w;                 w += (size_t)N_NODES * 4;
    float* sbuf = (float*)w;                 w += (size_t)N_NODES * 4;
    float* q    = (float*)w;                 w += (size_t)N_NODES * 32 * 4;
    float* gsum = (float*)w;                 w += (size_t)N_GRAPHS * 32 * 4;
    float* gcnt = (float*)w;                 w += (size_t)N_GRAPHS * 4;

    hipMemsetAsync(bhist, 0, (size_t)NBUCK * 4, stream);
    hipMemsetAsync(gsum, 0, (size_t)N_GRAPHS * 32 * 4, stream);

    const int B = 256;
    k_bhist<<<512, B, 0, stream>>>(dstIdx, bhist);
    k_scan <<<1, 1024, 0, stream>>>(bhist, off, cur);
    k_part <<<(N_EDGES + B - 1) / B, B, 0, stream>>>(srcIdx, dstIdx, cur, packed);
    k_gcnt <<<1, 128, 0, stream>>>(batch, gcnt);
    k_deg  <<<NBUCK, B, 0, stream>>>(off, packed, x, dinv, sbuf);
    k_l1   <<<NBUCK, B, 0, stream>>>(off, packed, dinv, sbuf, W1, b1, W2, q);
    k_l2   <<<NBUCK, B, 0, stream>>>(off, packed, q, dinv, b2, batch, gsum);
    k_readout<<<1, 64, 0, stream>>>(gsum, gcnt, Wfc, bfc, out);
}

// Round 4
// 921.668 us; speedup vs baseline: 1.7323x; 1.7323x over previous
//
#include <hip/hip_runtime.h>
#include <math.h>

#define N_NODES 100000
#define N_EDGES 3200000
#define N_GRAPHS 64
#define BW 256                               // nodes per bucket
#define NBUCK ((N_NODES + BW - 1) / BW)      // 391
#define CHUNK_E 8192
#define NCHUNK ((N_EDGES + CHUNK_E - 1) / CHUNK_E)  // 391

// ---- pass A: per-chunk bucket histogram (LDS only; 1 global row write) ----
__global__ void k_count(const int* __restrict__ dst, unsigned int* __restrict__ counts,
                        unsigned int* __restrict__ totals) {
    __shared__ unsigned int h[NBUCK];
    for (int i = threadIdx.x; i < NBUCK; i += blockDim.x) h[i] = 0u;
    __syncthreads();
    int e0 = blockIdx.x * CHUNK_E;
    int e1 = min(e0 + CHUNK_E, N_EDGES);
    for (int e = e0 + threadIdx.x; e < e1; e += blockDim.x)
        atomicAdd(&h[dst[e] >> 8], 1u);
    __syncthreads();
    for (int i = threadIdx.x; i < NBUCK; i += blockDim.x) {
        counts[(size_t)blockIdx.x * NBUCK + i] = h[i];
        if (h[i]) atomicAdd(&totals[i], h[i]);
    }
}

// ---- pass B: exclusive scan of bucket totals -> base ----
__global__ void k_scanb(const unsigned int* __restrict__ totals, unsigned int* __restrict__ base) {
    __shared__ unsigned int sd[512];
    int t = threadIdx.x;
    unsigned int v = (t < NBUCK) ? totals[t] : 0u;
    sd[t] = v;
    __syncthreads();
    for (int o = 1; o < 512; o <<= 1) {
        unsigned int tv = (t >= o) ? sd[t - o] : 0u;
        __syncthreads();
        sd[t] += tv;
        __syncthreads();
    }
    if (t < NBUCK) base[t] = sd[t] - v;
    if (t == 0) base[NBUCK] = N_EDGES;
}

// ---- pass C: per-bucket scan over chunks -> counts becomes start[chunk][bucket] ----
__global__ void k_scanc(unsigned int* __restrict__ counts, const unsigned int* __restrict__ base) {
    __shared__ unsigned int sd[512];
    int bk = blockIdx.x;
    int t = threadIdx.x;
    unsigned int v = (t < NCHUNK) ? counts[(size_t)t * NBUCK + bk] : 0u;
    sd[t] = v;
    __syncthreads();
    for (int o = 1; o < 512; o <<= 1) {
        unsigned int tv = (t >= o) ? sd[t - o] : 0u;
        __syncthreads();
        sd[t] += tv;
        __syncthreads();
    }
    if (t < NCHUNK) counts[(size_t)t * NBUCK + bk] = base[bk] + sd[t] - v;
}

// ---- pass D: place edges — ZERO global atomics ----
__global__ void k_part(const int* __restrict__ src, const int* __restrict__ dst,
                       const unsigned int* __restrict__ counts, unsigned int* __restrict__ packed) {
    __shared__ unsigned int sstart[NBUCK];
    __shared__ unsigned int lcur[NBUCK];
    for (int i = threadIdx.x; i < NBUCK; i += blockDim.x) {
        sstart[i] = counts[(size_t)blockIdx.x * NBUCK + i];
        lcur[i] = 0u;
    }
    __syncthreads();
    int e0 = blockIdx.x * CHUNK_E;
    int e1 = min(e0 + CHUNK_E, N_EDGES);
    for (int e = e0 + threadIdx.x; e < e1; e += blockDim.x) {
        int d = dst[e];
        int bk = d >> 8;
        unsigned int pos = sstart[bk] + atomicAdd(&lcur[bk], 1u);
        packed[pos] = ((unsigned int)src[e] << 8) | (unsigned int)(d & 255);
    }
}

// ---- per-bucket degree -> dinv, s ----
__global__ void k_deg(const unsigned int* __restrict__ base, const unsigned int* __restrict__ packed,
                      const float* __restrict__ x, float* __restrict__ dinv, float* __restrict__ s) {
    __shared__ unsigned int cnt[BW];
    cnt[threadIdx.x] = 0u;   // blockDim == BW == 256
    __syncthreads();
    int b = blockIdx.x;
    unsigned int e0 = base[b], e1 = base[b + 1];
    for (unsigned int e = e0 + threadIdx.x; e < e1; e += blockDim.x)
        atomicAdd(&cnt[packed[e] & 255u], 1u);
    __syncthreads();
    int n = b * BW + threadIdx.x;
    if (n < N_NODES) {
        float di = 1.0f / sqrtf((float)(cnt[threadIdx.x] + 1u));  // +1 self-loop
        dinv[n] = di;
        s[n] = x[n] * di;
    }
}

// ---- graph node counts via binary search (no atomics) ----
__global__ void k_gcnt(const int* __restrict__ batch, float* __restrict__ gcnt) {
    __shared__ int lb[N_GRAPHS + 1];
    int b = threadIdx.x;
    if (b <= N_GRAPHS) {
        int lo = 0, hi = N_NODES;
        while (lo < hi) {
            int mid = (lo + hi) >> 1;
            if (batch[mid] < b) lo = mid + 1; else hi = mid;
        }
        lb[b] = lo;
    }
    __syncthreads();
    if (b < N_GRAPHS) gcnt[b] = (float)(lb[b + 1] - lb[b]);
}

// ---- layer 1: LDS scalar agg + fused node MLP -> q ----
__global__ void k_l1(const unsigned int* __restrict__ base, const unsigned int* __restrict__ packed,
                     const float* __restrict__ dinv, const float* __restrict__ s,
                     const float* __restrict__ W1, const float* __restrict__ b1,
                     const float* __restrict__ W2, float* __restrict__ q) {
    __shared__ float acc[BW];
    __shared__ float sW2[64 * 32];
    __shared__ float sW1[64], sb1[64];
    acc[threadIdx.x] = 0.0f;
    for (int i = threadIdx.x; i < 64 * 32; i += blockDim.x) sW2[i] = W2[i];
    if (threadIdx.x < 64) { sW1[threadIdx.x] = W1[threadIdx.x]; sb1[threadIdx.x] = b1[threadIdx.x]; }
    __syncthreads();
    int b = blockIdx.x;
    unsigned int e0 = base[b], e1 = base[b + 1];
    for (unsigned int e = e0 + threadIdx.x; e < e1; e += blockDim.x) {
        unsigned int p = packed[e];
        atomicAdd(&acc[p & 255u], s[p >> 8]);
    }
    __syncthreads();
    int t = threadIdx.x;
    int n = b * BW + t;
    if (n < N_NODES) {
        float di = dinv[n];
        float tt = di * (acc[t] + s[n]);
        float p[32];
#pragma unroll
        for (int k = 0; k < 32; k++) p[k] = 0.0f;
        for (int j = 0; j < 64; j++) {
            float h = fmaxf(tt * sW1[j] + sb1[j], 0.0f);
#pragma unroll
            for (int k = 0; k < 32; k++) p[k] += h * sW2[j * 32 + k];
        }
#pragma unroll
        for (int k = 0; k < 32; k++) q[(size_t)n * 32 + k] = p[k] * di;
    }
}

// ---- layer 2: LDS row agg + relu + fused pooling ----
__global__ void k_l2(const unsigned int* __restrict__ base, const unsigned int* __restrict__ packed,
                     const float* __restrict__ q, const float* __restrict__ dinv,
                     const float* __restrict__ b2, const int* __restrict__ batch,
                     float* __restrict__ gsum) {
    __shared__ float acc[BW * 32];  // 32 KB
    for (int i = threadIdx.x; i < BW * 32; i += blockDim.x) acc[i] = 0.0f;
    __syncthreads();
    int b = blockIdx.x;
    unsigned int e0 = base[b], e1 = base[b + 1];
    int g = threadIdx.x >> 5;   // 8 groups of 32 lanes
    int k = threadIdx.x & 31;
    for (unsigned int e = e0 + g; e < e1; e += 8) {
        unsigned int p = packed[e];                     // broadcast within group
        int local = (int)(p & 255u);
        int src = (int)(p >> 8);
        atomicAdd(&acc[local * 32 + k], q[(size_t)src * 32 + k]);  // lane k -> bank k
    }
    __syncthreads();
    // relu + run-accumulated pooling (batch sorted)
    float racc = 0.0f;
    int curg = -1;
    for (int i = g; i < BW; i += 8) {
        int n = b * BW + i;
        if (n >= N_NODES) break;
        float v = fmaxf(dinv[n] * (acc[i * 32 + k] + q[(size_t)n * 32 + k]) + b2[k], 0.0f);
        int gb = batch[n];
        if (gb != curg) {
            if (curg >= 0) atomicAdd(&gsum[curg * 32 + k], racc);
            racc = 0.0f; curg = gb;
        }
        racc += v;
    }
    if (curg >= 0) atomicAdd(&gsum[curg * 32 + k], racc);
}

// ---- readout ----
__global__ void k_readout(const float* __restrict__ gsum, const float* __restrict__ gcnt,
                          const float* __restrict__ Wfc, const float* __restrict__ bfc,
                          float* __restrict__ out) {
    int b = threadIdx.x;
    if (b < N_GRAPHS) {
        float inv = 1.0f / fmaxf(gcnt[b], 1.0f);
        float acc = bfc[0];
#pragma unroll
        for (int k = 0; k < 32; k++) acc += gsum[b * 32 + k] * inv * Wfc[k];
        out[b] = 1.0f / (1.0f + expf(-acc));
    }
}

// ---- launch ----
extern "C" void kernel_launch(void* const* d_in, const int* in_sizes, int n_in,
                              void* d_out, int out_size, void* d_ws, size_t ws_size,
                              hipStream_t stream) {
    const float* x    = (const float*)d_in[0];
    const int*   ei   = (const int*)d_in[1];
    const int*   batch= (const int*)d_in[2];
    const float* W1   = (const float*)d_in[3];
    const float* b1   = (const float*)d_in[4];
    const float* W2   = (const float*)d_in[5];
    const float* b2   = (const float*)d_in[6];
    const float* Wfc  = (const float*)d_in[7];
    const float* bfc  = (const float*)d_in[8];
    float* out = (float*)d_out;

    const int* srcIdx = ei;
    const int* dstIdx = ei + N_EDGES;

    char* w = (char*)d_ws;
    unsigned int* counts = (unsigned int*)w; w += ((size_t)NCHUNK * NBUCK + 64) * 4;
    unsigned int* totals = (unsigned int*)w; w += ((NBUCK + 64) & ~63) * 4;
    unsigned int* base   = (unsigned int*)w; w += ((NBUCK + 1 + 63) & ~63) * 4;
    unsigned int* packed = (unsigned int*)w; w += (size_t)N_EDGES * 4;
    float* dinv = (float*)w;                 w += (size_t)N_NODES * 4;
    float* sbuf = (float*)w;                 w += (size_t)N_NODES * 4;
    float* q    = (float*)w;                 w += (size_t)N_NODES * 32 * 4;
    float* gsum = (float*)w;                 w += (size_t)N_GRAPHS * 32 * 4;
    float* gcnt = (float*)w;                 w += (size_t)N_GRAPHS * 4;

    hipMemsetAsync(totals, 0, (size_t)NBUCK * 4, stream);
    hipMemsetAsync(gsum, 0, (size_t)N_GRAPHS * 32 * 4, stream);

    const int B = 256;
    k_count<<<NCHUNK, B, 0, stream>>>(dstIdx, counts, totals);
    k_scanb<<<1, 512, 0, stream>>>(totals, base);
    k_scanc<<<NBUCK, 512, 0, stream>>>(counts, base);
    k_part <<<NCHUNK, B, 0, stream>>>(srcIdx, dstIdx, counts, packed);
    k_gcnt <<<1, 128, 0, stream>>>(batch, gcnt);
    k_deg  <<<NBUCK, B, 0, stream>>>(base, packed, x, dinv, sbuf);
    k_l1   <<<NBUCK, B, 0, stream>>>(base, packed, dinv, sbuf, W1, b1, W2, q);
    k_l2   <<<NBUCK, B, 0, stream>>>(base, packed, q, dinv, b2, batch, gsum);
    k_readout<<<1, 64, 0, stream>>>(gsum, gcnt, Wfc, bfc, out);
}

// Round 5
// 881.267 us; speedup vs baseline: 1.8117x; 1.0458x over previous
//
#include <hip/hip_runtime.h>
#include <math.h>

#define N_NODES 100000
#define N_EDGES 3200000
#define N_GRAPHS 64
#define BW 128                               // nodes per bucket
#define LSH 7
#define LMASK 127u
#define NBUCK ((N_NODES + BW - 1) / BW)      // 782
#define CHUNK_E 8192
#define NCHUNK ((N_EDGES + CHUNK_E - 1) / CHUNK_E)  // 391

// ---- pass A: per-chunk bucket histogram (LDS only) ----
__global__ void k_count(const int* __restrict__ dst, unsigned int* __restrict__ counts,
                        unsigned int* __restrict__ totals) {
    __shared__ unsigned int h[NBUCK];
    for (int i = threadIdx.x; i < NBUCK; i += blockDim.x) h[i] = 0u;
    __syncthreads();
    int e0 = blockIdx.x * CHUNK_E;
    int e1 = min(e0 + CHUNK_E, N_EDGES);
    for (int e = e0 + threadIdx.x; e < e1; e += blockDim.x)
        atomicAdd(&h[dst[e] >> LSH], 1u);
    __syncthreads();
    for (int i = threadIdx.x; i < NBUCK; i += blockDim.x) {
        counts[(size_t)blockIdx.x * NBUCK + i] = h[i];
        if (h[i]) atomicAdd(&totals[i], h[i]);
    }
}

// ---- pass B: exclusive scan of bucket totals -> base ----
__global__ void k_scanb(const unsigned int* __restrict__ totals, unsigned int* __restrict__ base) {
    __shared__ unsigned int sd[1024];
    int t = threadIdx.x;
    unsigned int v = (t < NBUCK) ? totals[t] : 0u;
    sd[t] = v;
    __syncthreads();
    for (int o = 1; o < 1024; o <<= 1) {
        unsigned int tv = (t >= o) ? sd[t - o] : 0u;
        __syncthreads();
        sd[t] += tv;
        __syncthreads();
    }
    if (t < NBUCK) base[t] = sd[t] - v;
    if (t == 0) base[NBUCK] = N_EDGES;
}

// ---- pass C: per-bucket scan over chunks -> counts becomes start[chunk][bucket] ----
__global__ void k_scanc(unsigned int* __restrict__ counts, const unsigned int* __restrict__ base) {
    __shared__ unsigned int sd[512];
    int bk = blockIdx.x;
    int t = threadIdx.x;
    unsigned int v = (t < NCHUNK) ? counts[(size_t)t * NBUCK + bk] : 0u;
    sd[t] = v;
    __syncthreads();
    for (int o = 1; o < 512; o <<= 1) {
        unsigned int tv = (t >= o) ? sd[t - o] : 0u;
        __syncthreads();
        sd[t] += tv;
        __syncthreads();
    }
    if (t < NCHUNK) counts[(size_t)t * NBUCK + bk] = base[bk] + sd[t] - v;
}

// ---- pass D: place edges — zero global atomics ----
__global__ void k_part(const int* __restrict__ src, const int* __restrict__ dst,
                       const unsigned int* __restrict__ counts, unsigned int* __restrict__ packed) {
    __shared__ unsigned int sstart[NBUCK];
    __shared__ unsigned int lcur[NBUCK];
    for (int i = threadIdx.x; i < NBUCK; i += blockDim.x) {
        sstart[i] = counts[(size_t)blockIdx.x * NBUCK + i];
        lcur[i] = 0u;
    }
    __syncthreads();
    int e0 = blockIdx.x * CHUNK_E;
    int e1 = min(e0 + CHUNK_E, N_EDGES);
    for (int e = e0 + threadIdx.x; e < e1; e += blockDim.x) {
        int d = dst[e];
        int bk = d >> LSH;
        unsigned int pos = sstart[bk] + atomicAdd(&lcur[bk], 1u);
        packed[pos] = ((unsigned int)src[e] << LSH) | ((unsigned int)d & LMASK);
    }
}

// ---- per-bucket degree -> dinv, s ----
__global__ void k_deg(const unsigned int* __restrict__ base, const unsigned int* __restrict__ packed,
                      const float* __restrict__ x, float* __restrict__ dinv, float* __restrict__ s) {
    __shared__ unsigned int cnt[BW];
    if (threadIdx.x < BW) cnt[threadIdx.x] = 0u;
    __syncthreads();
    int b = blockIdx.x;
    unsigned int e0 = base[b], e1 = base[b + 1];
    for (unsigned int e = e0 + threadIdx.x; e < e1; e += blockDim.x)
        atomicAdd(&cnt[packed[e] & LMASK], 1u);
    __syncthreads();
    int n = b * BW + threadIdx.x;
    if (threadIdx.x < BW && n < N_NODES) {
        float di = 1.0f / sqrtf((float)(cnt[threadIdx.x] + 1u));  // +1 self-loop
        dinv[n] = di;
        s[n] = x[n] * di;
    }
}

// ---- graph node counts via binary search (no atomics) ----
__global__ void k_gcnt(const int* __restrict__ batch, float* __restrict__ gcnt) {
    __shared__ int lb[N_GRAPHS + 1];
    int b = threadIdx.x;
    if (b <= N_GRAPHS) {
        int lo = 0, hi = N_NODES;
        while (lo < hi) {
            int mid = (lo + hi) >> 1;
            if (batch[mid] < b) lo = mid + 1; else hi = mid;
        }
        lb[b] = lo;
    }
    __syncthreads();
    if (b < N_GRAPHS) gcnt[b] = (float)(lb[b + 1] - lb[b]);
}

// ---- layer 1: LDS scalar agg + fused node MLP -> q ----
__global__ void k_l1(const unsigned int* __restrict__ base, const unsigned int* __restrict__ packed,
                     const float* __restrict__ dinv, const float* __restrict__ s,
                     const float* __restrict__ W1, const float* __restrict__ b1,
                     const float* __restrict__ W2, float* __restrict__ q) {
    __shared__ float acc[BW];
    __shared__ float sW2[64 * 32];
    __shared__ float sW1[64], sb1[64];
    if (threadIdx.x < BW) acc[threadIdx.x] = 0.0f;
    for (int i = threadIdx.x; i < 64 * 32; i += blockDim.x) sW2[i] = W2[i];
    if (threadIdx.x < 64) { sW1[threadIdx.x] = W1[threadIdx.x]; sb1[threadIdx.x] = b1[threadIdx.x]; }
    __syncthreads();
    int b = blockIdx.x;
    unsigned int e0 = base[b], e1 = base[b + 1];
    for (unsigned int e = e0 + threadIdx.x; e < e1; e += blockDim.x) {
        unsigned int p = packed[e];
        atomicAdd(&acc[p & LMASK], s[p >> LSH]);
    }
    __syncthreads();
    int t = threadIdx.x;
    int n = b * BW + t;
    if (t < BW && n < N_NODES) {
        float di = dinv[n];
        float tt = di * (acc[t] + s[n]);
        float p[32];
#pragma unroll
        for (int k = 0; k < 32; k++) p[k] = 0.0f;
        for (int j = 0; j < 64; j++) {
            float h = fmaxf(tt * sW1[j] + sb1[j], 0.0f);
#pragma unroll
            for (int k = 0; k < 32; k++) p[k] += h * sW2[j * 32 + k];
        }
#pragma unroll
        for (int k = 0; k < 32; k++) q[(size_t)n * 32 + k] = p[k] * di;
    }
}

// ---- layer 2: LDS row agg (8-way MLP-unrolled gather) + relu + fused pooling ----
__global__ void k_l2(const unsigned int* __restrict__ base, const unsigned int* __restrict__ packed,
                     const float* __restrict__ q, const float* __restrict__ dinv,
                     const float* __restrict__ b2, const int* __restrict__ batch,
                     float* __restrict__ gsum) {
    __shared__ float acc[BW * 32];  // 16 KB
    for (int i = threadIdx.x; i < BW * 32; i += blockDim.x) acc[i] = 0.0f;
    __syncthreads();
    int b = blockIdx.x;
    unsigned int e0 = base[b], e1 = base[b + 1];
    int g = threadIdx.x >> 5;   // 8 groups of 32 lanes
    int k = threadIdx.x & 31;

    unsigned int e = e0 + (unsigned int)g * 8u;
    for (; e + 8 <= e1; e += 64) {
        // 8 consecutive packed words: 1-2 broadcast transactions
        unsigned int p0 = packed[e + 0], p1 = packed[e + 1], p2 = packed[e + 2], p3 = packed[e + 3];
        unsigned int p4 = packed[e + 4], p5 = packed[e + 5], p6 = packed[e + 6], p7 = packed[e + 7];
        // 8 independent 128B row loads in flight
        float v0 = q[(size_t)(p0 >> LSH) * 32 + k];
        float v1 = q[(size_t)(p1 >> LSH) * 32 + k];
        float v2 = q[(size_t)(p2 >> LSH) * 32 + k];
        float v3 = q[(size_t)(p3 >> LSH) * 32 + k];
        float v4 = q[(size_t)(p4 >> LSH) * 32 + k];
        float v5 = q[(size_t)(p5 >> LSH) * 32 + k];
        float v6 = q[(size_t)(p6 >> LSH) * 32 + k];
        float v7 = q[(size_t)(p7 >> LSH) * 32 + k];
        atomicAdd(&acc[(p0 & LMASK) * 32 + k], v0);  // lane k -> bank k, conflict-free
        atomicAdd(&acc[(p1 & LMASK) * 32 + k], v1);
        atomicAdd(&acc[(p2 & LMASK) * 32 + k], v2);
        atomicAdd(&acc[(p3 & LMASK) * 32 + k], v3);
        atomicAdd(&acc[(p4 & LMASK) * 32 + k], v4);
        atomicAdd(&acc[(p5 & LMASK) * 32 + k], v5);
        atomicAdd(&acc[(p6 & LMASK) * 32 + k], v6);
        atomicAdd(&acc[(p7 & LMASK) * 32 + k], v7);
    }
    // tail: the one partial 8-block belongs to exactly one group
    unsigned int te = (e1 < e + 8) ? e1 : (e + 8);
    for (unsigned int j = e; j < te; j++) {
        unsigned int p = packed[j];
        atomicAdd(&acc[(p & LMASK) * 32 + k], q[(size_t)(p >> LSH) * 32 + k]);
    }
    __syncthreads();

    // relu + run-accumulated pooling (batch sorted)
    float racc = 0.0f;
    int curg = -1;
    for (int i = g; i < BW; i += 8) {
        int n = b * BW + i;
        if (n >= N_NODES) break;
        float v = fmaxf(dinv[n] * (acc[i * 32 + k] + q[(size_t)n * 32 + k]) + b2[k], 0.0f);
        int gb = batch[n];
        if (gb != curg) {
            if (curg >= 0) atomicAdd(&gsum[curg * 32 + k], racc);
            racc = 0.0f; curg = gb;
        }
        racc += v;
    }
    if (curg >= 0) atomicAdd(&gsum[curg * 32 + k], racc);
}

// ---- readout ----
__global__ void k_readout(const float* __restrict__ gsum, const float* __restrict__ gcnt,
                          const float* __restrict__ Wfc, const float* __restrict__ bfc,
                          float* __restrict__ out) {
    int b = threadIdx.x;
    if (b < N_GRAPHS) {
        float inv = 1.0f / fmaxf(gcnt[b], 1.0f);
        float acc = bfc[0];
#pragma unroll
        for (int k = 0; k < 32; k++) acc += gsum[b * 32 + k] * inv * Wfc[k];
        out[b] = 1.0f / (1.0f + expf(-acc));
    }
}

// ---- launch ----
extern "C" void kernel_launch(void* const* d_in, const int* in_sizes, int n_in,
                              void* d_out, int out_size, void* d_ws, size_t ws_size,
                              hipStream_t stream) {
    const float* x    = (const float*)d_in[0];
    const int*   ei   = (const int*)d_in[1];
    const int*   batch= (const int*)d_in[2];
    const float* W1   = (const float*)d_in[3];
    const float* b1   = (const float*)d_in[4];
    const float* W2   = (const float*)d_in[5];
    const float* b2   = (const float*)d_in[6];
    const float* Wfc  = (const float*)d_in[7];
    const float* bfc  = (const float*)d_in[8];
    float* out = (float*)d_out;

    const int* srcIdx = ei;
    const int* dstIdx = ei + N_EDGES;

    char* w = (char*)d_ws;
    unsigned int* counts = (unsigned int*)w; w += ((size_t)NCHUNK * NBUCK + 64) * 4;
    unsigned int* totals = (unsigned int*)w; w += ((NBUCK + 64) & ~63) * 4;
    unsigned int* base   = (unsigned int*)w; w += ((NBUCK + 1 + 63) & ~63) * 4;
    unsigned int* packed = (unsigned int*)w; w += (size_t)N_EDGES * 4;
    float* dinv = (float*)w;                 w += (size_t)N_NODES * 4;
    float* sbuf = (float*)w;                 w += (size_t)N_NODES * 4;
    float* q    = (float*)w;                 w += (size_t)N_NODES * 32 * 4;
    float* gsum = (float*)w;                 w += (size_t)N_GRAPHS * 32 * 4;
    float* gcnt = (float*)w;                 w += (size_t)N_GRAPHS * 4;

    hipMemsetAsync(totals, 0, (size_t)NBUCK * 4, stream);
    hipMemsetAsync(gsum, 0, (size_t)N_GRAPHS * 32 * 4, stream);

    const int B = 256;
    k_count<<<NCHUNK, B, 0, stream>>>(dstIdx, counts, totals);
    k_scanb<<<1, 1024, 0, stream>>>(totals, base);
    k_scanc<<<NBUCK, 512, 0, stream>>>(counts, base);
    k_part <<<NCHUNK, B, 0, stream>>>(srcIdx, dstIdx, counts, packed);
    k_gcnt <<<1, 128, 0, stream>>>(batch, gcnt);
    k_deg  <<<NBUCK, B, 0, stream>>>(base, packed, x, dinv, sbuf);
    k_l1   <<<NBUCK, B, 0, stream>>>(base, packed, dinv, sbuf, W1, b1, W2, q);
    k_l2   <<<NBUCK, B, 0, stream>>>(base, packed, q, dinv, b2, batch, gsum);
    k_readout<<<1, 64, 0, stream>>>(gsum, gcnt, Wfc, bfc, out);
}